// Round 8
// baseline (256.189 us; speedup 1.0000x reference)
//
#include <hip/hip_runtime.h>

#define SMOOTH 1e-8f

typedef float f32x4 __attribute__((ext_vector_type(4)));

// Fixed problem shape: [N, C, Z, X, Y] = [4, 2, 160, 160, 160]
constexpr int NROWS = 8000;            // per-(16^3 block, channel) rows
constexpr int WG1   = 1600;            // half-slab workgroups

// Kernel 1: half-slab (n,c,zz,xx, 8 z-planes). Each WAVE owns TWO z-plane
// slab rows (A: plane h*8+w, quarter 2h; B: plane h*8+4+w, quarter 2h+1),
// each row = 640 contiguous f4 (10 KB). Issue all 20 nt loads of A, then all
// 20 of B (sched_barrier-pinned), THEN consume A (B stays in flight: FIFO
// vmcnt), consume B, single tail per 40 KB.
// Binning algebra per row (verified R7): load k, lane -> f4 slot
// j = (lane + 24k) mod 40, j === lane (mod 8); yy = j>>2 = 2r + b with
// r = j>>3 (period 5 in k), b = (lane>>2)&1 (thread-fixed).
__global__ __launch_bounds__(256, 2)
void partial_kernel(const float* __restrict__ pred,
                    const float* __restrict__ gt,
                    float* __restrict__ wsq)
{
    int wg = blockIdx.x;
    const int h  = wg & 1;  wg >>= 1;
    const int c  = wg & 1;  wg >>= 1;
    const int xx = wg % 10; wg /= 10;
    const int zz = wg % 10;
    const int n  = wg / 10;

    const int t    = threadIdx.x;
    const int lane = t & 63;
    const int wave = t >> 6;
    const int zA   = zz * 16 + h * 8 + wave;    // row A plane (quarter 2h)
    const int zB   = zA + 4;                    // row B plane (quarter 2h+1)

    const long pbA = ((long)((n * 2 + c) * 160 + zA) * 160 + xx * 16) * 40L;
    const long pbB = ((long)((n * 2 + c) * 160 + zB) * 160 + xx * 16) * 40L;

    const f32x4* pA = reinterpret_cast<const f32x4*>(pred) + pbA + lane;
    const f32x4* gA = reinterpret_cast<const f32x4*>(gt)  + pbA + lane;
    const f32x4* pB = reinterpret_cast<const f32x4*>(pred) + pbB + lane;
    const f32x4* gB = reinterpret_cast<const f32x4*>(gt)  + pbB + lane;

    // ---- issue phase: 40 unit-stride 1KB nt loads, order pinned ----
    f32x4 PA[10], GA[10], PB[10], GB[10];
    #pragma unroll
    for (int k = 0; k < 10; ++k) {
        PA[k] = __builtin_nontemporal_load(pA + k * 64);
        GA[k] = __builtin_nontemporal_load(gA + k * 64);
    }
    __builtin_amdgcn_sched_barrier(0);
    #pragma unroll
    for (int k = 0; k < 10; ++k) {
        PB[k] = __builtin_nontemporal_load(pB + k * 64);
        GB[k] = __builtin_nontemporal_load(gB + k * 64);
    }
    __builtin_amdgcn_sched_barrier(0);

    // ---- consume A (B still in flight), then B; m = k mod 5 static ----
    float aSA[5] = {0,0,0,0,0}, aGA[5] = {0,0,0,0,0}, aPA[5] = {0,0,0,0,0};
    float aSB[5] = {0,0,0,0,0}, aGB[5] = {0,0,0,0,0}, aPB[5] = {0,0,0,0,0};
    #pragma unroll
    for (int k = 0; k < 10; ++k) {
        const int m = k % 5;
        const f32x4 p = PA[k], g = GA[k];
        aSA[m] += (p.x + p.y) + (p.z + p.w);
        aGA[m] += (g.x + g.y) + (g.z + g.w);
        aPA[m] += p.x * g.x + p.y * g.y + p.z * g.z + p.w * g.w;
    }
    #pragma unroll
    for (int k = 0; k < 10; ++k) {
        const int m = k % 5;
        const f32x4 p = PB[k], g = GB[k];
        aSB[m] += (p.x + p.y) + (p.z + p.w);
        aGB[m] += (g.x + g.y) + (g.z + g.w);
        aPB[m] += p.x * g.x + p.y * g.y + p.z * g.z + p.w * g.w;
    }

    // ---- rotate m-indexed triplets into r-indexed (yy = 2r + b) ----
    int rr[5];
    #pragma unroll
    for (int m = 0; m < 5; ++m)
        rr[m] = ((lane + 24 * m) % 40) >> 3;    // runtime value, static index

    float bSA[5], bGA[5], bPA[5], bSB[5], bGB[5], bPB[5];
    #pragma unroll
    for (int r = 0; r < 5; ++r) {
        float s0 = 0, g0 = 0, p0 = 0, s1 = 0, g1 = 0, p1 = 0;
        #pragma unroll
        for (int m = 0; m < 5; ++m) {
            const bool hit = (rr[m] == r);      // exactly one m matches
            s0 += hit ? aSA[m] : 0.f;  g0 += hit ? aGA[m] : 0.f;
            p0 += hit ? aPA[m] : 0.f;
            s1 += hit ? aSB[m] : 0.f;  g1 += hit ? aGB[m] : 0.f;
            p1 += hit ? aPB[m] : 0.f;
        }
        bSA[r] = s0; bGA[r] = g0; bPA[r] = p0;
        bSB[r] = s1; bGB[r] = g1; bPB[r] = p1;
    }

    // ---- xor-reduce over lane bits {0,1,3,4,5}: preserves b = bit2 ----
    #pragma unroll
    for (int r = 0; r < 5; ++r) {
        #pragma unroll
        for (int d = 0; d < 5; ++d) {
            const int msk = (d < 2) ? (1 << d) : (1 << (d + 1));  // 1,2,8,16,32
            bSA[r] += __shfl_xor(bSA[r], msk, 64);
            bGA[r] += __shfl_xor(bGA[r], msk, 64);
            bPA[r] += __shfl_xor(bPA[r], msk, 64);
            bSB[r] += __shfl_xor(bSB[r], msk, 64);
            bGB[r] += __shfl_xor(bGB[r], msk, 64);
            bPB[r] += __shfl_xor(bPB[r], msk, 64);
        }
    }

    __shared__ float red[4][2][2][15];          // [wave][A/B][b][r*3+comp]
    const int b = (lane >> 2) & 1;
    if ((lane & 59) == 0) {                     // lanes 0 (b=0) and 4 (b=1)
        #pragma unroll
        for (int r = 0; r < 5; ++r) {
            red[wave][0][b][r * 3 + 0] = bSA[r];
            red[wave][0][b][r * 3 + 1] = bGA[r];
            red[wave][0][b][r * 3 + 2] = bPA[r];
            red[wave][1][b][r * 3 + 0] = bSB[r];
            red[wave][1][b][r * 3 + 1] = bGB[r];
            red[wave][1][b][r * 3 + 2] = bPB[r];
        }
    }
    __syncthreads();

    if (t < 60) {
        const int qq   = t / 30;                // 0: quarter 2h, 1: quarter 2h+1
        const int rem  = t - qq * 30;
        const int yy   = rem / 3;
        const int comp = rem - yy * 3;
        const int bb = yy & 1, r = yy >> 1;
        const float val =
            red[0][qq][bb][r * 3 + comp] + red[1][qq][bb][r * 3 + comp] +
            red[2][qq][bb][r * 3 + comp] + red[3][qq][bb][r * 3 + comp];
        const int row = (((n * 10 + zz) * 10 + xx) * 10 + yy) * 2 + c;
        const int q4  = 2 * h + qq;
        wsq[(row * 4 + q4) * 3 + comp] = val;   // distinct slot, no atomic
    }
}

// Kernel 2: single WG — combine quarters, nonlinear term, write out[0].
__global__ __launch_bounds__(1024)
void finalize_kernel(const float* __restrict__ wsq,
                     const float* __restrict__ a_p,
                     const float* __restrict__ b_p,
                     float* __restrict__ out)
{
    const int t = threadIdx.x;
    const float a = a_p[0], b = b_p[0];
    float sum = 0.f;

    for (int r = t; r < NROWS; r += 1024) {
        const float4 w0 = *reinterpret_cast<const float4*>(wsq + r * 12);
        const float4 w1 = *reinterpret_cast<const float4*>(wsq + r * 12 + 4);
        const float4 w2 = *reinterpret_cast<const float4*>(wsq + r * 12 + 8);
        const float SP  = w0.x + w0.w + w1.z + w2.y;
        const float SG  = w0.y + w1.x + w1.w + w2.z;
        const float SGP = w0.z + w1.y + w2.x + w2.w;

        const float tp = SGP;
        const float fn = SG - SGP;
        const float fp = SP - SGP;
        const float denom = fp + fn + SMOOTH;
        const float alpha = a + b * ((fp + SMOOTH) / denom);
        const float beta  = a + b * ((fn + SMOOTH) / denom);
        sum += 1.f - (tp + SMOOTH) / (tp + alpha * fp + beta * fn + SMOOTH);
    }

    #pragma unroll
    for (int d = 32; d > 0; d >>= 1) sum += __shfl_down(sum, d, 64);

    __shared__ float wsum[16];
    if ((t & 63) == 0) wsum[t >> 6] = sum;
    __syncthreads();
    if (t == 0) {
        float tot = 0.f;
        #pragma unroll
        for (int i = 0; i < 16; ++i) tot += wsum[i];
        out[0] = tot;
    }
}

extern "C" void kernel_launch(void* const* d_in, const int* in_sizes, int n_in,
                              void* d_out, int out_size, void* d_ws, size_t ws_size,
                              hipStream_t stream)
{
    const float* pred = (const float*)d_in[0];
    const float* gt   = (const float*)d_in[1];
    const float* a_p  = (const float*)d_in[2];
    const float* b_p  = (const float*)d_in[3];
    float* out = (float*)d_out;
    float* wsq = (float*)d_ws;   // 8000 rows * 4 quarters * 3 sums = 384 KB

    partial_kernel<<<WG1, 256, 0, stream>>>(pred, gt, wsq);
    finalize_kernel<<<1, 1024, 0, stream>>>(wsq, a_p, b_p, out);
}